// Round 1
// baseline (214.447 us; speedup 1.0000x reference)
//
#include <hip/hip_runtime.h>

// EdgeLoss: loss = mean|Sobel_x(d)| + mean|Sobel_y(d)|, d = gray(sr) - gray(hr)
// Linearity: gray and conv commute with subtraction, so compute d once.
// B=32, C=3, H=W=512. Memory-bound: 201 MB mandatory read.

#define TH 16                 // output rows per block
#define TILE_ROWS (TH + 2)    // +2 halo rows
#define ROWSTRIDE 516         // 512 + 2 pad cols + 2 align pad (keeps rows 16B-aligned)

__global__ __launch_bounds__(256, 4)
void edge_loss_kernel(const float* __restrict__ sr, const float* __restrict__ hr,
                      float* __restrict__ out) {
    __shared__ float tile[TILE_ROWS][ROWSTRIDE];
    const int tid   = threadIdx.x;
    const int img   = blockIdx.x >> 5;   // 32 strips per image
    const int strip = blockIdx.x & 31;
    const int row0  = strip * TH;

    // zero the left/right padding columns (image x-boundary zeros)
    if (tid < TILE_ROWS) { tile[tid][0] = 0.f; tile[tid][513] = 0.f; }

    const size_t imgBase = (size_t)img * (3 * 512 * 512);
    const float* __restrict__ srp = sr + imgBase;
    const float* __restrict__ hrp = hr + imgBase;

    // Stage gray-diff tile: 18 rows x 512 cols, float4 per thread-iteration.
    // 18*128 = 2304 float4 groups, 9 iterations of 256 threads. Coalesced.
    for (int idx = tid; idx < TILE_ROWS * 128; idx += 256) {
        const int r  = idx >> 7;          // tile row 0..17
        const int x4 = (idx & 127) << 2;  // col 0,4,...,508
        const int gr = row0 - 1 + r;      // global row (-1..512)
        float dx = 0.f, dy = 0.f, dz = 0.f, dw = 0.f;
        if (gr >= 0 && gr < 512) {
            const size_t off = (size_t)gr * 512 + x4;
            const float4 sR = *(const float4*)(srp + off);
            const float4 sG = *(const float4*)(srp + off + 262144);
            const float4 sB = *(const float4*)(srp + off + 524288);
            const float4 hR = *(const float4*)(hrp + off);
            const float4 hG = *(const float4*)(hrp + off + 262144);
            const float4 hB = *(const float4*)(hrp + off + 524288);
            dx = 0.2989f*(sR.x-hR.x) + 0.587f*(sG.x-hG.x) + 0.114f*(sB.x-hB.x);
            dy = 0.2989f*(sR.y-hR.y) + 0.587f*(sG.y-hG.y) + 0.114f*(sB.y-hB.y);
            dz = 0.2989f*(sR.z-hR.z) + 0.587f*(sG.z-hG.z) + 0.114f*(sB.z-hB.z);
            dw = 0.2989f*(sR.w-hR.w) + 0.587f*(sG.w-hG.w) + 0.114f*(sB.w-hB.w);
        }
        float* t = &tile[r][1 + x4];      // +1 shift for left pad col
        t[0] = dx; t[1] = dy; t[2] = dz; t[3] = dw;
    }
    __syncthreads();

    // Each thread computes 8 groups of 4 output pixels: 16 rows x 128 groups.
    float acc = 0.f;
    #pragma unroll
    for (int i = 0; i < 8; ++i) {
        const int g  = tid + (i << 8);
        const int r  = g >> 7;            // output row 0..15 (tile center row r+1)
        const int x4 = (g & 127) << 2;    // tile col base (covers image x-1..x+4)
        const float* A  = &tile[r][x4];       // row above
        const float* Bc = &tile[r + 1][x4];   // center
        const float* Cc = &tile[r + 2][x4];   // below
        const float a0=A[0],a1=A[1],a2=A[2],a3=A[3],a4=A[4],a5=A[5];
        const float b0=Bc[0],b1=Bc[1],b2=Bc[2],b3=Bc[3],b4=Bc[4],b5=Bc[5];
        const float c0=Cc[0],c1=Cc[1],c2=Cc[2],c3=Cc[3],c4=Cc[4],c5=Cc[5];
        // column sums (vertical [1,2,1]) -> gx = s[x-1] - s[x+1]
        const float s0=a0+2.f*b0+c0, s1=a1+2.f*b1+c1, s2=a2+2.f*b2+c2,
                    s3=a3+2.f*b3+c3, s4=a4+2.f*b4+c4, s5=a5+2.f*b5+c5;
        acc += fabsf(s0 - s2) + fabsf(s1 - s3) + fabsf(s2 - s4) + fabsf(s3 - s5);
        // gy = horiz [1,2,1] of row above - row below (abs kills kernel-flip sign)
        acc += fabsf((a0 + 2.f*a1 + a2) - (c0 + 2.f*c1 + c2));
        acc += fabsf((a1 + 2.f*a2 + a3) - (c1 + 2.f*c2 + c3));
        acc += fabsf((a2 + 2.f*a3 + a4) - (c2 + 2.f*c3 + c4));
        acc += fabsf((a3 + 2.f*a4 + a5) - (c3 + 2.f*c4 + c5));
    }

    // wave reduce (64 lanes) then block reduce, one atomic per block
    #pragma unroll
    for (int o = 32; o > 0; o >>= 1) acc += __shfl_down(acc, o, 64);
    __shared__ float wsum[4];
    if ((tid & 63) == 0) wsum[tid >> 6] = acc;
    __syncthreads();
    if (tid == 0) {
        const float s = (wsum[0] + wsum[1] + wsum[2] + wsum[3]) * (1.0f / 8388608.0f);
        atomicAdd(out, s);
    }
}

extern "C" void kernel_launch(void* const* d_in, const int* in_sizes, int n_in,
                              void* d_out, int out_size, void* d_ws, size_t ws_size,
                              hipStream_t stream) {
    const float* sr = (const float*)d_in[0];
    const float* hr = (const float*)d_in[1];
    float* out = (float*)d_out;
    // d_out is poisoned 0xAA before every launch; zero it (memset node is graph-capturable)
    hipMemsetAsync(out, 0, sizeof(float), stream);
    edge_loss_kernel<<<dim3(32 * 32), dim3(256), 0, stream>>>(sr, hr, out);
}